// Round 4
// baseline (5868.264 us; speedup 1.0000x reference)
//
#include <hip/hip_runtime.h>

#define DIM 64
#define RPB 64            // rows per bucket
#define MAXB 8192         // max buckets (nNodes <= 8192*64 = 2^19, also packing limit)

__device__ __forceinline__ float i2f(int x) { union { int i; float f; } u; u.i = x; return u.f; }

// ---------------- bucket histogram (LDS-aggregated) ----------------
__global__ __launch_bounds__(256) void k_bhist(const int* __restrict__ rows,
                                               int* __restrict__ bCnt, int nE, int nB) {
    __shared__ int h[MAXB];
    for (int j = threadIdx.x; j < nB; j += 256) h[j] = 0;
    __syncthreads();
    for (long i = (long)blockIdx.x * blockDim.x + threadIdx.x; i < nE;
         i += (long)gridDim.x * blockDim.x)
        atomicAdd(&h[rows[i] >> 6], 1);
    __syncthreads();
    for (int j = threadIdx.x; j < nB; j += 256) {
        int v = h[j];
        if (v) atomicAdd(&bCnt[j], v);
    }
}

// ---------------- single-block scan over buckets ----------------
__global__ __launch_bounds__(1024) void k_bscan(const int* __restrict__ bCnt,
                                                int* __restrict__ bStart,
                                                int* __restrict__ bCur, int nB, int nE) {
    __shared__ int s[1024];
    __shared__ int carry;
    if (threadIdx.x == 0) carry = 0;
    __syncthreads();
    for (int base = 0; base < nB; base += 1024) {
        int i = base + threadIdx.x;
        int v = (i < nB) ? bCnt[i] : 0;
        s[threadIdx.x] = v;
        __syncthreads();
        for (int off = 1; off < 1024; off <<= 1) {
            int t = (threadIdx.x >= (unsigned)off) ? s[threadIdx.x - off] : 0;
            __syncthreads();
            s[threadIdx.x] += t;
            __syncthreads();
        }
        int excl = carry + s[threadIdx.x] - v;
        if (i < nB) { bStart[i] = excl; bCur[i] = excl; }
        __syncthreads();
        if (threadIdx.x == 1023) carry += s[1023];
        __syncthreads();
    }
    if (threadIdx.x == 0) bStart[nB] = nE;
}

// ---------------- scatter into bucket-ordered pairs ----------------
// pairs[pos] = ( (localRow<<19) | col , bits(val) )
__global__ __launch_bounds__(256) void k_scatter2(const int* __restrict__ rows,
                                                  const int* __restrict__ cols,
                                                  const float* __restrict__ vals,
                                                  int* __restrict__ bCur,
                                                  int2* __restrict__ pairs, int nE) {
    int i = blockIdx.x * blockDim.x + threadIdx.x;
    if (i < nE) {
        int r = rows[i];
        int pos = atomicAdd(&bCur[r >> 6], 1);
        pairs[pos] = make_int2(((r & 63) << 19) | cols[i], __float_as_int(vals[i]));
    }
}

// ---------------- hop 1: block per bucket, LDS tile accumulate ----------------
__global__ __launch_bounds__(256) void k_spmm_b1(const int* __restrict__ bStart,
                                                 const int2* __restrict__ pairs,
                                                 const float* __restrict__ uE,
                                                 const float* __restrict__ iE,
                                                 float* __restrict__ cur1,
                                                 int nNodes, int nUsers) {
    __shared__ float tile[RPB * DIM];     // 16 KB
    const int lane = threadIdx.x & 63;
    const int wid  = threadIdx.x >> 6;    // 0..3
    float4* t4 = (float4*)tile;
    for (int i = threadIdx.x; i < RPB * DIM / 4; i += 256) t4[i] = make_float4(0, 0, 0, 0);
    __syncthreads();
    const int start = bStart[blockIdx.x], end = bStart[blockIdx.x + 1];
    for (int e = start + wid * 2; e < end; e += 8) {
        int2 p0 = pairs[e];
        bool has1 = (e + 1 < end);
        int2 p1 = has1 ? pairs[e + 1] : make_int2(0, 0);
        {
            int c = p0.x & 0x7FFFF;
            const float* src = (c < nUsers) ? uE + (size_t)c * DIM
                                            : iE + (size_t)(c - nUsers) * DIM;
            atomicAdd(&tile[(p0.x >> 19) * DIM + lane], i2f(p0.y) * src[lane]);
        }
        if (has1) {
            int c = p1.x & 0x7FFFF;
            const float* src = (c < nUsers) ? uE + (size_t)c * DIM
                                            : iE + (size_t)(c - nUsers) * DIM;
            atomicAdd(&tile[(p1.x >> 19) * DIM + lane], i2f(p1.y) * src[lane]);
        }
    }
    __syncthreads();
    const size_t base = (size_t)blockIdx.x * RPB * DIM;   // element offset
    long remain = (long)nNodes * DIM - (long)base;
    int n4 = (int)min((long)(RPB * DIM / 4), remain / 4);
    float4* dst = (float4*)(cur1 + base);
    for (int i = threadIdx.x; i < n4; i += 256) dst[i] = t4[i];
}

// ---------------- hop 2 + fused epilogue ----------------
__global__ __launch_bounds__(256) void k_spmm_b2(const int* __restrict__ bStart,
                                                 const int2* __restrict__ pairs,
                                                 const float* __restrict__ cur1,
                                                 const float* __restrict__ uE,
                                                 const float* __restrict__ iE,
                                                 float* __restrict__ out,
                                                 int nNodes, int nUsers) {
    __shared__ float tile[RPB * DIM];
    const int lane = threadIdx.x & 63;
    const int wid  = threadIdx.x >> 6;
    float4* t4 = (float4*)tile;
    for (int i = threadIdx.x; i < RPB * DIM / 4; i += 256) t4[i] = make_float4(0, 0, 0, 0);
    __syncthreads();
    const int start = bStart[blockIdx.x], end = bStart[blockIdx.x + 1];
    for (int e = start + wid * 2; e < end; e += 8) {
        int2 p0 = pairs[e];
        bool has1 = (e + 1 < end);
        int2 p1 = has1 ? pairs[e + 1] : make_int2(0, 0);
        {
            int c = p0.x & 0x7FFFF;
            atomicAdd(&tile[(p0.x >> 19) * DIM + lane],
                      i2f(p0.y) * cur1[(size_t)c * DIM + lane]);
        }
        if (has1) {
            int c = p1.x & 0x7FFFF;
            atomicAdd(&tile[(p1.x >> 19) * DIM + lane],
                      i2f(p1.y) * cur1[(size_t)c * DIM + lane]);
        }
    }
    __syncthreads();
    const int r0 = blockIdx.x * RPB;
    const float inv3 = 1.0f / 3.0f;
    for (int p = 0; p < 4; ++p) {
        int lr = p * 16 + (threadIdx.x >> 4);
        int c4 = threadIdx.x & 15;
        int r = r0 + lr;
        if (r < nNodes) {
            float4 tv = ((float4*)tile)[lr * 16 + c4];
            float4 c1 = ((const float4*)cur1)[(size_t)r * 16 + c4];
            float4 em = (r < nUsers)
                            ? ((const float4*)uE)[(size_t)r * 16 + c4]
                            : ((const float4*)iE)[(size_t)(r - nUsers) * 16 + c4];
            float4 o;
            o.x = (em.x + c1.x + tv.x) * inv3;
            o.y = (em.y + c1.y + tv.y) * inv3;
            o.z = (em.z + c1.z + tv.z) * inv3;
            o.w = (em.w + c1.w + tv.w) * inv3;
            ((float4*)out)[(size_t)r * 16 + c4] = o;
        }
    }
}

// ---------------- fallback (round-1 atomic path) ----------------
__global__ __launch_bounds__(256) void spmm_scatter(
    const int* __restrict__ rows, const int* __restrict__ cols,
    const float* __restrict__ vals, const float* __restrict__ srcU,
    const float* __restrict__ srcI, float* __restrict__ dst,
    float scale, int nEdges, int nUsers)
{
    const int lane = threadIdx.x & 63;
    const int wavesPerBlock = blockDim.x >> 6;
    long wave = (long)blockIdx.x * wavesPerBlock + (threadIdx.x >> 6);
    const long nWaves = (long)gridDim.x * wavesPerBlock;
    for (long e = wave; e < nEdges; e += nWaves) {
        const int r = rows[e];
        const int c = cols[e];
        const float v = vals[e] * scale;
        const float* src;
        if (srcI != nullptr) {
            src = (c < nUsers) ? (srcU + (size_t)c * DIM)
                               : (srcI + (size_t)(c - nUsers) * DIM);
        } else {
            src = srcU + (size_t)c * DIM;
        }
        atomicAdd(dst + (size_t)r * DIM + lane, v * src[lane]);
    }
}

__global__ __launch_bounds__(256) void finalize_base(
    const float* __restrict__ userE, const float* __restrict__ itemE,
    const float* __restrict__ cur1, float* __restrict__ out, int nNodes, int nUsers)
{
    const long total4 = (long)nNodes * DIM / 4;
    const long user4  = (long)nUsers * DIM / 4;
    const float inv3 = 1.0f / 3.0f;
    for (long i = (long)blockIdx.x * blockDim.x + threadIdx.x; i < total4;
         i += (long)gridDim.x * blockDim.x) {
        float4 e = (i < user4) ? ((const float4*)userE)[i]
                               : ((const float4*)itemE)[i - user4];
        float4 c = ((const float4*)cur1)[i];
        float4 o;
        o.x = (e.x + c.x) * inv3; o.y = (e.y + c.y) * inv3;
        o.z = (e.z + c.z) * inv3; o.w = (e.w + c.w) * inv3;
        ((float4*)out)[i] = o;
    }
}

// ----------------------------------------------------------------

static inline size_t align256(size_t x) { return (x + 255) & ~(size_t)255; }

extern "C" void kernel_launch(void* const* d_in, const int* in_sizes, int n_in,
                              void* d_out, int out_size, void* d_ws, size_t ws_size,
                              hipStream_t stream)
{
    const int*   rows  = (const int*)d_in[0];
    const int*   cols  = (const int*)d_in[1];
    const float* vals  = (const float*)d_in[2];
    const float* userE = (const float*)d_in[3];
    const float* itemE = (const float*)d_in[4];
    float* out = (float*)d_out;

    const int nE     = in_sizes[0];
    const int nUsers = in_sizes[3] / DIM;
    const int nItems = in_sizes[4] / DIM;
    const int nNodes = nUsers + nItems;
    const int nB     = (nNodes + RPB - 1) / RPB;

    // workspace layout
    const size_t cur1Off = 0;
    const size_t cur1B   = (size_t)nNodes * DIM * sizeof(float);
    const size_t cntOff  = align256(cur1Off + cur1B);
    const size_t cntB    = (size_t)MAXB * sizeof(int);
    const size_t bsOff   = align256(cntOff + cntB);
    const size_t bsB     = ((size_t)MAXB + 1) * sizeof(int);
    const size_t bcOff   = align256(bsOff + bsB);
    const size_t bcB     = (size_t)MAXB * sizeof(int);
    const size_t pairOff = align256(bcOff + bcB);
    const size_t pairB   = (size_t)nE * sizeof(int2);
    const size_t required = pairOff + pairB;

    char* ws = (char*)d_ws;
    float* cur1 = (float*)(ws + cur1Off);

    if (ws_size >= required && nNodes <= MAXB * RPB) {
        int*  bCnt   = (int*)(ws + cntOff);
        int*  bStart = (int*)(ws + bsOff);
        int*  bCur   = (int*)(ws + bcOff);
        int2* pairs  = (int2*)(ws + pairOff);

        hipMemsetAsync(bCnt, 0, (size_t)nB * sizeof(int), stream);
        k_bhist<<<dim3(256), dim3(256), 0, stream>>>(rows, bCnt, nE, nB);
        k_bscan<<<dim3(1), dim3(1024), 0, stream>>>(bCnt, bStart, bCur, nB, nE);
        k_scatter2<<<dim3((nE + 255) / 256), dim3(256), 0, stream>>>(rows, cols, vals,
                                                                     bCur, pairs, nE);
        k_spmm_b1<<<dim3(nB), dim3(256), 0, stream>>>(bStart, pairs, userE, itemE,
                                                      cur1, nNodes, nUsers);
        k_spmm_b2<<<dim3(nB), dim3(256), 0, stream>>>(bStart, pairs, cur1, userE, itemE,
                                                      out, nNodes, nUsers);
    } else {
        // fallback: atomic scatter path (round-1)
        hipMemsetAsync(cur1, 0, cur1B, stream);
        dim3 blk(256);
        spmm_scatter<<<dim3(4096), blk, 0, stream>>>(rows, cols, vals, userE, itemE,
                                                     cur1, 1.0f, nE, nUsers);
        finalize_base<<<dim3(2048), blk, 0, stream>>>(userE, itemE, cur1, out,
                                                      nNodes, nUsers);
        spmm_scatter<<<dim3(4096), blk, 0, stream>>>(rows, cols, vals, cur1, nullptr,
                                                     out, 1.0f / 3.0f, nE, nUsers);
    }
}

// Round 5
// 1465.445 us; speedup vs baseline: 4.0044x; 4.0044x over previous
//
#include <hip/hip_runtime.h>

#define DIM 64

__device__ __forceinline__ float i2f(int x) { union { int i; float f; } u; u.i = x; return u.f; }

// ---------------- per-row histogram ----------------
__global__ __launch_bounds__(256) void k_hist(const int* __restrict__ rows,
                                              int* __restrict__ counts, int nE) {
    int i = blockIdx.x * blockDim.x + threadIdx.x;
    if (i < nE) atomicAdd(&counts[rows[i]], 1);
}

// per-block exclusive scan of counts -> excl, block totals -> blockSums
__global__ __launch_bounds__(1024) void k_scan1(const int* __restrict__ counts,
                                                int* __restrict__ excl,
                                                int* __restrict__ blockSums, int n) {
    __shared__ int s[1024];
    int i = blockIdx.x * 1024 + threadIdx.x;
    int v = (i < n) ? counts[i] : 0;
    s[threadIdx.x] = v; __syncthreads();
    for (int off = 1; off < 1024; off <<= 1) {
        int t = (threadIdx.x >= (unsigned)off) ? s[threadIdx.x - off] : 0;
        __syncthreads();
        s[threadIdx.x] += t;
        __syncthreads();
    }
    if (i < n) excl[i] = s[threadIdx.x] - v;
    if (threadIdx.x == 1023) blockSums[blockIdx.x] = s[1023];
}

__global__ __launch_bounds__(512) void k_scan2(const int* __restrict__ blockSums,
                                               int* __restrict__ blockOffs, int nB,
                                               int* __restrict__ rowStartEnd, int total) {
    __shared__ int s[512];
    int v = ((int)threadIdx.x < nB) ? blockSums[threadIdx.x] : 0;
    s[threadIdx.x] = v; __syncthreads();
    for (int off = 1; off < 512; off <<= 1) {
        int t = (threadIdx.x >= (unsigned)off) ? s[threadIdx.x - off] : 0;
        __syncthreads();
        s[threadIdx.x] += t;
        __syncthreads();
    }
    if ((int)threadIdx.x < nB) blockOffs[threadIdx.x] = s[threadIdx.x] - v;
    if (threadIdx.x == 0) *rowStartEnd = total;
}

__global__ __launch_bounds__(1024) void k_scan3(int* __restrict__ excl,
                                                const int* __restrict__ blockOffs, int n) {
    int i = blockIdx.x * 1024 + threadIdx.x;
    if (i < n) excl[i] += blockOffs[blockIdx.x];
}

// ---------------- bucket cursors (padded: 1 per 64B line) ----------------
__global__ __launch_bounds__(256) void k_bcur(const int* __restrict__ rowStart,
                                              int* __restrict__ bCurPad,
                                              int nBuck, int nNodes) {
    int b = blockIdx.x * blockDim.x + threadIdx.x;
    if (b < nBuck) {
        int r = b * 64; if (r > nNodes) r = nNodes;
        bCurPad[b * 16] = rowStart[r];
    }
}

// ---------------- phase 1: COO -> bucket-ordered pairs ----------------
// pairsA[pos] = ( (localRow<<19) | col , bits(val) ); positions within a bucket
// are sequential (cursor starts at rowStart[64b]) -> full-line writes.
__global__ __launch_bounds__(256) void k_scatterA(const int* __restrict__ rows,
                                                  const int* __restrict__ cols,
                                                  const float* __restrict__ vals,
                                                  int* __restrict__ bCurPad,
                                                  int2* __restrict__ pairsA, int nE) {
    int i = blockIdx.x * blockDim.x + threadIdx.x;
    if (i < nE) {
        int r = rows[i];
        int pos = atomicAdd(&bCurPad[(r >> 6) * 16], 1);
        pairsA[pos] = make_int2(((r & 63) << 19) | cols[i], __float_as_int(vals[i]));
    }
}

// ---------------- phase 2: bucket-ordered -> exact CSR ----------------
// block per bucket; reads sequential, writes land in the bucket's contiguous
// CSR span (~14KB, L2-resident). LDS int atomics give within-row ranks.
__global__ __launch_bounds__(256) void k_reorder(const int* __restrict__ rowStart,
                                                 const int2* __restrict__ pairsA,
                                                 int2* __restrict__ pairsCSR,
                                                 int nNodes) {
    __shared__ int rsL[65];
    __shared__ int cnt[64];
    const int b = blockIdx.x;
    const int r0 = b * 64;
    if (threadIdx.x < 65) {
        int r = r0 + threadIdx.x; if (r > nNodes) r = nNodes;
        rsL[threadIdx.x] = rowStart[r];
    }
    if (threadIdx.x < 64) cnt[threadIdx.x] = 0;
    __syncthreads();
    const int segStart = rsL[0];
    const int segEnd   = rsL[64];
    for (int i = segStart + threadIdx.x; i < segEnd; i += 256) {
        int2 p = pairsA[i];
        int lr = p.x >> 19;
        int rank = atomicAdd(&cnt[lr], 1);
        pairsCSR[rsL[lr] + rank] = make_int2(p.x & 0x7FFFF, p.y);
    }
}

// ---------------- SpMM: one wave per row, lane = dim, unroll x4 ----------------
__global__ __launch_bounds__(256) void k_spmm1(const int* __restrict__ rowStart,
                                               const int2* __restrict__ pairs,
                                               const float* __restrict__ uE,
                                               const float* __restrict__ iE,
                                               float* __restrict__ cur1,
                                               int nNodes, int nUsers) {
    const int lane = threadIdx.x & 63;
    int r = blockIdx.x * (blockDim.x >> 6) + (threadIdx.x >> 6);
    if (r >= nNodes) return;
    int start = __builtin_amdgcn_readfirstlane(rowStart[r]);
    int end   = __builtin_amdgcn_readfirstlane(rowStart[r + 1]);
    float acc = 0.f;
    int e = start;
    for (; e + 3 < end; e += 4) {
        int2 p0 = pairs[e], p1 = pairs[e + 1], p2 = pairs[e + 2], p3 = pairs[e + 3];
        const float* s0 = (p0.x < nUsers) ? uE + (size_t)p0.x * DIM
                                          : iE + (size_t)(p0.x - nUsers) * DIM;
        const float* s1 = (p1.x < nUsers) ? uE + (size_t)p1.x * DIM
                                          : iE + (size_t)(p1.x - nUsers) * DIM;
        const float* s2 = (p2.x < nUsers) ? uE + (size_t)p2.x * DIM
                                          : iE + (size_t)(p2.x - nUsers) * DIM;
        const float* s3 = (p3.x < nUsers) ? uE + (size_t)p3.x * DIM
                                          : iE + (size_t)(p3.x - nUsers) * DIM;
        float x0 = s0[lane], x1 = s1[lane], x2 = s2[lane], x3 = s3[lane];
        acc = fmaf(i2f(p0.y), x0, acc);
        acc = fmaf(i2f(p1.y), x1, acc);
        acc = fmaf(i2f(p2.y), x2, acc);
        acc = fmaf(i2f(p3.y), x3, acc);
    }
    for (; e < end; ++e) {
        int2 p = pairs[e];
        const float* s = (p.x < nUsers) ? uE + (size_t)p.x * DIM
                                        : iE + (size_t)(p.x - nUsers) * DIM;
        acc = fmaf(i2f(p.y), s[lane], acc);
    }
    cur1[(size_t)r * DIM + lane] = acc;
}

__global__ __launch_bounds__(256) void k_spmm2(const int* __restrict__ rowStart,
                                               const int2* __restrict__ pairs,
                                               const float* __restrict__ cur1,
                                               const float* __restrict__ uE,
                                               const float* __restrict__ iE,
                                               float* __restrict__ out,
                                               int nNodes, int nUsers) {
    const int lane = threadIdx.x & 63;
    int r = blockIdx.x * (blockDim.x >> 6) + (threadIdx.x >> 6);
    if (r >= nNodes) return;
    int start = __builtin_amdgcn_readfirstlane(rowStart[r]);
    int end   = __builtin_amdgcn_readfirstlane(rowStart[r + 1]);
    float acc = 0.f;
    int e = start;
    for (; e + 3 < end; e += 4) {
        int2 p0 = pairs[e], p1 = pairs[e + 1], p2 = pairs[e + 2], p3 = pairs[e + 3];
        float x0 = cur1[(size_t)p0.x * DIM + lane];
        float x1 = cur1[(size_t)p1.x * DIM + lane];
        float x2 = cur1[(size_t)p2.x * DIM + lane];
        float x3 = cur1[(size_t)p3.x * DIM + lane];
        acc = fmaf(i2f(p0.y), x0, acc);
        acc = fmaf(i2f(p1.y), x1, acc);
        acc = fmaf(i2f(p2.y), x2, acc);
        acc = fmaf(i2f(p3.y), x3, acc);
    }
    for (; e < end; ++e) {
        int2 p = pairs[e];
        acc = fmaf(i2f(p.y), cur1[(size_t)p.x * DIM + lane], acc);
    }
    float em = (r < nUsers) ? uE[(size_t)r * DIM + lane]
                            : iE[(size_t)(r - nUsers) * DIM + lane];
    out[(size_t)r * DIM + lane] = (em + cur1[(size_t)r * DIM + lane] + acc) * (1.0f / 3.0f);
}

// ---------------- fallback (round-1 atomic path) ----------------
__global__ __launch_bounds__(256) void spmm_scatter(
    const int* __restrict__ rows, const int* __restrict__ cols,
    const float* __restrict__ vals, const float* __restrict__ srcU,
    const float* __restrict__ srcI, float* __restrict__ dst,
    float scale, int nEdges, int nUsers)
{
    const int lane = threadIdx.x & 63;
    const int wavesPerBlock = blockDim.x >> 6;
    long wave = (long)blockIdx.x * wavesPerBlock + (threadIdx.x >> 6);
    const long nWaves = (long)gridDim.x * wavesPerBlock;
    for (long e = wave; e < nEdges; e += nWaves) {
        const int r = rows[e];
        const int c = cols[e];
        const float v = vals[e] * scale;
        const float* src;
        if (srcI != nullptr) {
            src = (c < nUsers) ? (srcU + (size_t)c * DIM)
                               : (srcI + (size_t)(c - nUsers) * DIM);
        } else {
            src = srcU + (size_t)c * DIM;
        }
        atomicAdd(dst + (size_t)r * DIM + lane, v * src[lane]);
    }
}

__global__ __launch_bounds__(256) void finalize_base(
    const float* __restrict__ userE, const float* __restrict__ itemE,
    const float* __restrict__ cur1, float* __restrict__ out, int nNodes, int nUsers)
{
    const long total4 = (long)nNodes * DIM / 4;
    const long user4  = (long)nUsers * DIM / 4;
    const float inv3 = 1.0f / 3.0f;
    for (long i = (long)blockIdx.x * blockDim.x + threadIdx.x; i < total4;
         i += (long)gridDim.x * blockDim.x) {
        float4 e = (i < user4) ? ((const float4*)userE)[i]
                               : ((const float4*)itemE)[i - user4];
        float4 c = ((const float4*)cur1)[i];
        float4 o;
        o.x = (e.x + c.x) * inv3; o.y = (e.y + c.y) * inv3;
        o.z = (e.z + c.z) * inv3; o.w = (e.w + c.w) * inv3;
        ((float4*)out)[i] = o;
    }
}

// ----------------------------------------------------------------

static inline size_t align256(size_t x) { return (x + 255) & ~(size_t)255; }

extern "C" void kernel_launch(void* const* d_in, const int* in_sizes, int n_in,
                              void* d_out, int out_size, void* d_ws, size_t ws_size,
                              hipStream_t stream)
{
    const int*   rows  = (const int*)d_in[0];
    const int*   cols  = (const int*)d_in[1];
    const float* vals  = (const float*)d_in[2];
    const float* userE = (const float*)d_in[3];
    const float* itemE = (const float*)d_in[4];
    float* out = (float*)d_out;

    const int nE     = in_sizes[0];
    const int nUsers = in_sizes[3] / DIM;
    const int nItems = in_sizes[4] / DIM;
    const int nNodes = nUsers + nItems;
    const int nBuck  = (nNodes + 63) / 64;

    // ws layout:
    //   [cur1 region: max(cur1, pairsA)]  pairsA lives here first, spmm1 then
    //                                     overwrites it with cur1 (pairsA dead)
    //   [pairs region: pairsCSR]
    //   [counts][rowStart][bCurPad][blockSums][blockOffs]
    const size_t cur1B    = (size_t)nNodes * DIM * sizeof(float);     // 76.8MB
    const size_t pairsAB  = (size_t)nE * sizeof(int2);                // 64MB
    const size_t reg0B    = cur1B > pairsAB ? cur1B : pairsAB;
    const size_t csrOff   = align256(reg0B);
    const size_t csrB     = (size_t)nE * sizeof(int2);
    const size_t cntOff   = align256(csrOff + csrB);
    const size_t cntB     = (size_t)nNodes * sizeof(int);
    const size_t rsOff    = align256(cntOff + cntB);
    const size_t rsB      = ((size_t)nNodes + 1) * sizeof(int);
    const size_t bcOff    = align256(rsOff + rsB);
    const size_t bcB      = (size_t)nBuck * 16 * sizeof(int);         // 64B-padded
    const size_t bsOff    = align256(bcOff + bcB);
    const size_t bsB      = 512 * sizeof(int);
    const size_t boOff    = align256(bsOff + bsB);
    const size_t boB      = 512 * sizeof(int);
    const size_t required = boOff + boB;

    char* ws = (char*)d_ws;
    float* cur1     = (float*)ws;
    int2*  pairsA   = (int2*)ws;                 // same region as cur1
    int2*  pairsCSR = (int2*)(ws + csrOff);

    if (ws_size >= required && nNodes < (1 << 19)) {
        int* counts    = (int*)(ws + cntOff);
        int* rowStart  = (int*)(ws + rsOff);
        int* bCurPad   = (int*)(ws + bcOff);
        int* blockSums = (int*)(ws + bsOff);
        int* blockOffs = (int*)(ws + boOff);

        const int nSB = (nNodes + 1023) / 1024;   // scan blocks (<=512)

        hipMemsetAsync(counts, 0, cntB, stream);
        k_hist<<<dim3((nE + 255) / 256), dim3(256), 0, stream>>>(rows, counts, nE);
        k_scan1<<<dim3(nSB), dim3(1024), 0, stream>>>(counts, rowStart, blockSums, nNodes);
        k_scan2<<<dim3(1), dim3(512), 0, stream>>>(blockSums, blockOffs, nSB,
                                                   rowStart + nNodes, nE);
        k_scan3<<<dim3(nSB), dim3(1024), 0, stream>>>(rowStart, blockOffs, nNodes);
        k_bcur<<<dim3((nBuck + 255) / 256), dim3(256), 0, stream>>>(rowStart, bCurPad,
                                                                    nBuck, nNodes);
        k_scatterA<<<dim3((nE + 255) / 256), dim3(256), 0, stream>>>(rows, cols, vals,
                                                                     bCurPad, pairsA, nE);
        k_reorder<<<dim3(nBuck), dim3(256), 0, stream>>>(rowStart, pairsA, pairsCSR,
                                                         nNodes);

        const int rowsPerBlock = 4;
        dim3 sgrid((nNodes + rowsPerBlock - 1) / rowsPerBlock), sblk(256);
        // spmm1 overwrites pairsA region with cur1 (pairsA is dead after reorder)
        k_spmm1<<<sgrid, sblk, 0, stream>>>(rowStart, pairsCSR, userE, itemE, cur1,
                                            nNodes, nUsers);
        k_spmm2<<<sgrid, sblk, 0, stream>>>(rowStart, pairsCSR, cur1, userE, itemE, out,
                                            nNodes, nUsers);
    } else {
        // fallback: atomic scatter path (round-1)
        hipMemsetAsync(cur1, 0, cur1B, stream);
        dim3 blk(256);
        spmm_scatter<<<dim3(4096), blk, 0, stream>>>(rows, cols, vals, userE, itemE,
                                                     cur1, 1.0f, nE, nUsers);
        finalize_base<<<dim3(2048), blk, 0, stream>>>(userE, itemE, cur1, out,
                                                      nNodes, nUsers);
        spmm_scatter<<<dim3(4096), blk, 0, stream>>>(rows, cols, vals, cur1, nullptr,
                                                     out, 1.0f / 3.0f, nE, nUsers);
    }
}

// Round 7
// 1140.972 us; speedup vs baseline: 5.1432x; 1.2844x over previous
//
#include <hip/hip_runtime.h>

#define DIM 64
#define PROWS 2048          // rows per partition (localRow fits 11 bits)
#define MAXPART 256         // supports nNodes <= 524288
#define CHUNK 8192          // edges per block in pass A (256 thr * 32)

__device__ __forceinline__ float i2f(int x) { union { int i; float f; } u; u.i = x; return u.f; }

// ---------------- per-row histogram ----------------
__global__ __launch_bounds__(256) void k_hist(const int* __restrict__ rows,
                                              int* __restrict__ counts, int nE) {
    int i = blockIdx.x * blockDim.x + threadIdx.x;
    if (i < nE) atomicAdd(&counts[rows[i]], 1);
}

// per-block exclusive scan of counts -> excl, block totals -> blockSums
__global__ __launch_bounds__(1024) void k_scan1(const int* __restrict__ counts,
                                                int* __restrict__ excl,
                                                int* __restrict__ blockSums, int n) {
    __shared__ int s[1024];
    int i = blockIdx.x * 1024 + threadIdx.x;
    int v = (i < n) ? counts[i] : 0;
    s[threadIdx.x] = v; __syncthreads();
    for (int off = 1; off < 1024; off <<= 1) {
        int t = (threadIdx.x >= (unsigned)off) ? s[threadIdx.x - off] : 0;
        __syncthreads();
        s[threadIdx.x] += t;
        __syncthreads();
    }
    if (i < n) excl[i] = s[threadIdx.x] - v;
    if (threadIdx.x == 1023) blockSums[blockIdx.x] = s[1023];
}

__global__ __launch_bounds__(512) void k_scan2(const int* __restrict__ blockSums,
                                               int* __restrict__ blockOffs, int nB,
                                               int* __restrict__ rowStartEnd, int total) {
    __shared__ int s[512];
    int v = ((int)threadIdx.x < nB) ? blockSums[threadIdx.x] : 0;
    s[threadIdx.x] = v; __syncthreads();
    for (int off = 1; off < 512; off <<= 1) {
        int t = (threadIdx.x >= (unsigned)off) ? s[threadIdx.x - off] : 0;
        __syncthreads();
        s[threadIdx.x] += t;
        __syncthreads();
    }
    if ((int)threadIdx.x < nB) blockOffs[threadIdx.x] = s[threadIdx.x] - v;
    if (threadIdx.x == 0) *rowStartEnd = total;
}

__global__ __launch_bounds__(1024) void k_scan3(int* __restrict__ excl,
                                                const int* __restrict__ blockOffs, int n) {
    int i = blockIdx.x * 1024 + threadIdx.x;
    if (i < n) excl[i] += blockOffs[blockIdx.x];
}

// ---------------- partition cursors (padded: 1 per 64B line) ----------------
__global__ __launch_bounds__(256) void k_pcur(const int* __restrict__ rowStart,
                                              int* __restrict__ partCurPad,
                                              int nPart, int nNodes) {
    int p = blockIdx.x * blockDim.x + threadIdx.x;
    if (p < nPart) {
        int r = p * PROWS; if (r > nNodes) r = nNodes;
        partCurPad[p * 16] = rowStart[r];
    }
}

// ---------------- pass A: COO -> partition-ordered pairs ----------------
// Block-chunked counting sort: per-block LDS histogram over partitions, one
// global atomic per (block, partition) reserves a contiguous run; run is
// written entirely by this block -> full-line writebacks.
__global__ __launch_bounds__(256) void k_scatterP(const int* __restrict__ rows,
                                                  const int* __restrict__ cols,
                                                  const float* __restrict__ vals,
                                                  int* __restrict__ partCurPad,
                                                  int2* __restrict__ pairsA,
                                                  int nE, int nPart) {
    __shared__ int hist[MAXPART];
    __shared__ int runBase[MAXPART];
    const int chunkBase = blockIdx.x * CHUNK;

    for (int t = threadIdx.x; t < nPart; t += 256) hist[t] = 0;
    __syncthreads();
    #pragma unroll
    for (int j = 0; j < CHUNK / 256; ++j) {
        int i = chunkBase + j * 256 + threadIdx.x;
        if (i < nE) atomicAdd(&hist[rows[i] >> 11], 1);
    }
    __syncthreads();
    for (int t = threadIdx.x; t < nPart; t += 256) {
        int h = hist[t];
        runBase[t] = h ? atomicAdd(&partCurPad[t * 16], h) : 0;
    }
    __syncthreads();
    for (int t = threadIdx.x; t < nPart; t += 256) hist[t] = 0;   // reuse as rank
    __syncthreads();
    #pragma unroll
    for (int j = 0; j < CHUNK / 256; ++j) {
        int i = chunkBase + j * 256 + threadIdx.x;
        if (i < nE) {
            int r = rows[i];
            int p = r >> 11;
            int rank = atomicAdd(&hist[p], 1);
            pairsA[runBase[p] + rank] =
                make_int2(((r & (PROWS - 1)) << 19) | cols[i], __float_as_int(vals[i]));
        }
    }
}

// ---------------- pass B: partition-ordered -> exact CSR ----------------
// Block per partition; sequential reads; random writes confined to the
// partition's ~440KB CSR span (single block -> single XCD L2 absorbs).
__global__ __launch_bounds__(1024) void k_reorderP(const int* __restrict__ rowStart,
                                                   const int2* __restrict__ pairsA,
                                                   int2* __restrict__ pairsCSR,
                                                   int nNodes) {
    __shared__ int cur[PROWS];
    const int r0 = blockIdx.x * PROWS;
    const int rN = min(PROWS, nNodes - r0);
    for (int t = threadIdx.x; t < rN; t += 1024) cur[t] = rowStart[r0 + t];
    __syncthreads();
    const int segStart = rowStart[r0];
    const int segEnd   = rowStart[min(r0 + PROWS, nNodes)];
    for (int i = segStart + (int)threadIdx.x; i < segEnd; i += 1024) {
        int2 e = pairsA[i];
        int lr = e.x >> 19;
        int pos = atomicAdd(&cur[lr], 1);
        pairsCSR[pos] = make_int2(e.x & 0x7FFFF, e.y);
    }
}

// ---------------- SpMM: one wave per row, lane = dim, unroll x4 ----------------
__global__ __launch_bounds__(256) void k_spmm1(const int* __restrict__ rowStart,
                                               const int2* __restrict__ pairs,
                                               const float* __restrict__ uE,
                                               const float* __restrict__ iE,
                                               float* __restrict__ cur1,
                                               int nNodes, int nUsers) {
    const int lane = threadIdx.x & 63;
    int r = blockIdx.x * (blockDim.x >> 6) + (threadIdx.x >> 6);
    if (r >= nNodes) return;
    int start = __builtin_amdgcn_readfirstlane(rowStart[r]);
    int end   = __builtin_amdgcn_readfirstlane(rowStart[r + 1]);
    float acc = 0.f;
    int e = start;
    for (; e + 3 < end; e += 4) {
        int2 p0 = pairs[e], p1 = pairs[e + 1], p2 = pairs[e + 2], p3 = pairs[e + 3];
        const float* s0 = (p0.x < nUsers) ? uE + (size_t)p0.x * DIM
                                          : iE + (size_t)(p0.x - nUsers) * DIM;
        const float* s1 = (p1.x < nUsers) ? uE + (size_t)p1.x * DIM
                                          : iE + (size_t)(p1.x - nUsers) * DIM;
        const float* s2 = (p2.x < nUsers) ? uE + (size_t)p2.x * DIM
                                          : iE + (size_t)(p2.x - nUsers) * DIM;
        const float* s3 = (p3.x < nUsers) ? uE + (size_t)p3.x * DIM
                                          : iE + (size_t)(p3.x - nUsers) * DIM;
        float x0 = s0[lane], x1 = s1[lane], x2 = s2[lane], x3 = s3[lane];
        acc = fmaf(i2f(p0.y), x0, acc);
        acc = fmaf(i2f(p1.y), x1, acc);
        acc = fmaf(i2f(p2.y), x2, acc);
        acc = fmaf(i2f(p3.y), x3, acc);
    }
    for (; e < end; ++e) {
        int2 p = pairs[e];
        const float* s = (p.x < nUsers) ? uE + (size_t)p.x * DIM
                                        : iE + (size_t)(p.x - nUsers) * DIM;
        acc = fmaf(i2f(p.y), s[lane], acc);
    }
    cur1[(size_t)r * DIM + lane] = acc;
}

__global__ __launch_bounds__(256) void k_spmm2(const int* __restrict__ rowStart,
                                               const int2* __restrict__ pairs,
                                               const float* __restrict__ cur1,
                                               const float* __restrict__ uE,
                                               const float* __restrict__ iE,
                                               float* __restrict__ out,
                                               int nNodes, int nUsers) {
    const int lane = threadIdx.x & 63;
    int r = blockIdx.x * (blockDim.x >> 6) + (threadIdx.x >> 6);
    if (r >= nNodes) return;
    int start = __builtin_amdgcn_readfirstlane(rowStart[r]);
    int end   = __builtin_amdgcn_readfirstlane(rowStart[r + 1]);
    float acc = 0.f;
    int e = start;
    for (; e + 3 < end; e += 4) {
        int2 p0 = pairs[e], p1 = pairs[e + 1], p2 = pairs[e + 2], p3 = pairs[e + 3];
        float x0 = cur1[(size_t)p0.x * DIM + lane];
        float x1 = cur1[(size_t)p1.x * DIM + lane];
        float x2 = cur1[(size_t)p2.x * DIM + lane];
        float x3 = cur1[(size_t)p3.x * DIM + lane];
        acc = fmaf(i2f(p0.y), x0, acc);
        acc = fmaf(i2f(p1.y), x1, acc);
        acc = fmaf(i2f(p2.y), x2, acc);
        acc = fmaf(i2f(p3.y), x3, acc);
    }
    for (; e < end; ++e) {
        int2 p = pairs[e];
        acc = fmaf(i2f(p.y), cur1[(size_t)p.x * DIM + lane], acc);
    }
    float em = (r < nUsers) ? uE[(size_t)r * DIM + lane]
                            : iE[(size_t)(r - nUsers) * DIM + lane];
    out[(size_t)r * DIM + lane] = (em + cur1[(size_t)r * DIM + lane] + acc) * (1.0f / 3.0f);
}

// ---------------- fallback (round-1 atomic path) ----------------
__global__ __launch_bounds__(256) void spmm_scatter(
    const int* __restrict__ rows, const int* __restrict__ cols,
    const float* __restrict__ vals, const float* __restrict__ srcU,
    const float* __restrict__ srcI, float* __restrict__ dst,
    float scale, int nEdges, int nUsers)
{
    const int lane = threadIdx.x & 63;
    const int wavesPerBlock = blockDim.x >> 6;
    long wave = (long)blockIdx.x * wavesPerBlock + (threadIdx.x >> 6);
    const long nWaves = (long)gridDim.x * wavesPerBlock;
    for (long e = wave; e < nEdges; e += nWaves) {
        const int r = rows[e];
        const int c = cols[e];
        const float v = vals[e] * scale;
        const float* src;
        if (srcI != nullptr) {
            src = (c < nUsers) ? (srcU + (size_t)c * DIM)
                               : (srcI + (size_t)(c - nUsers) * DIM);
        } else {
            src = srcU + (size_t)c * DIM;
        }
        atomicAdd(dst + (size_t)r * DIM + lane, v * src[lane]);
    }
}

__global__ __launch_bounds__(256) void finalize_base(
    const float* __restrict__ userE, const float* __restrict__ itemE,
    const float* __restrict__ cur1, float* __restrict__ out, int nNodes, int nUsers)
{
    const long total4 = (long)nNodes * DIM / 4;
    const long user4  = (long)nUsers * DIM / 4;
    const float inv3 = 1.0f / 3.0f;
    for (long i = (long)blockIdx.x * blockDim.x + threadIdx.x; i < total4;
         i += (long)gridDim.x * blockDim.x) {
        float4 e = (i < user4) ? ((const float4*)userE)[i]
                               : ((const float4*)itemE)[i - user4];
        float4 c = ((const float4*)cur1)[i];
        float4 o;
        o.x = (e.x + c.x) * inv3; o.y = (e.y + c.y) * inv3;
        o.z = (e.z + c.z) * inv3; o.w = (e.w + c.w) * inv3;
        ((float4*)out)[i] = o;
    }
}

// ----------------------------------------------------------------

static inline size_t align256(size_t x) { return (x + 255) & ~(size_t)255; }

extern "C" void kernel_launch(void* const* d_in, const int* in_sizes, int n_in,
                              void* d_out, int out_size, void* d_ws, size_t ws_size,
                              hipStream_t stream)
{
    const int*   rows  = (const int*)d_in[0];
    const int*   cols  = (const int*)d_in[1];
    const float* vals  = (const float*)d_in[2];
    const float* userE = (const float*)d_in[3];
    const float* itemE = (const float*)d_in[4];
    float* out = (float*)d_out;

    const int nE     = in_sizes[0];
    const int nUsers = in_sizes[3] / DIM;
    const int nItems = in_sizes[4] / DIM;
    const int nNodes = nUsers + nItems;
    const int nPart  = (nNodes + PROWS - 1) / PROWS;

    // ws layout:
    //   [region0: max(cur1, pairsA)]  pairsA first; spmm1 later overwrites with cur1
    //   [pairsCSR][counts][rowStart][partCurPad][blockSums][blockOffs]
    const size_t cur1B    = (size_t)nNodes * DIM * sizeof(float);
    const size_t pairsAB  = (size_t)nE * sizeof(int2);
    const size_t reg0B    = cur1B > pairsAB ? cur1B : pairsAB;
    const size_t csrOff   = align256(reg0B);
    const size_t csrB     = (size_t)nE * sizeof(int2);
    const size_t cntOff   = align256(csrOff + csrB);
    const size_t cntB     = (size_t)nNodes * sizeof(int);
    const size_t rsOff    = align256(cntOff + cntB);
    const size_t rsB      = ((size_t)nNodes + 1) * sizeof(int);
    const size_t pcOff    = align256(rsOff + rsB);
    const size_t pcB      = (size_t)MAXPART * 16 * sizeof(int);
    const size_t bsOff    = align256(pcOff + pcB);
    const size_t bsB      = 512 * sizeof(int);
    const size_t boOff    = align256(bsOff + bsB);
    const size_t boB      = 512 * sizeof(int);
    const size_t required = boOff + boB;

    char* ws = (char*)d_ws;
    float* cur1     = (float*)ws;
    int2*  pairsA   = (int2*)ws;                 // same region as cur1
    int2*  pairsCSR = (int2*)(ws + csrOff);

    if (ws_size >= required && nNodes <= MAXPART * PROWS && nNodes < (1 << 19)) {
        int* counts    = (int*)(ws + cntOff);
        int* rowStart  = (int*)(ws + rsOff);
        int* partCurPad= (int*)(ws + pcOff);
        int* blockSums = (int*)(ws + bsOff);
        int* blockOffs = (int*)(ws + boOff);

        const int nSB = (nNodes + 1023) / 1024;          // scan blocks (<=512)
        const int nChunks = (nE + CHUNK - 1) / CHUNK;

        hipMemsetAsync(counts, 0, cntB, stream);
        k_hist<<<dim3((nE + 255) / 256), dim3(256), 0, stream>>>(rows, counts, nE);
        k_scan1<<<dim3(nSB), dim3(1024), 0, stream>>>(counts, rowStart, blockSums, nNodes);
        k_scan2<<<dim3(1), dim3(512), 0, stream>>>(blockSums, blockOffs, nSB,
                                                   rowStart + nNodes, nE);
        k_scan3<<<dim3(nSB), dim3(1024), 0, stream>>>(rowStart, blockOffs, nNodes);
        k_pcur<<<dim3((nPart + 255) / 256), dim3(256), 0, stream>>>(rowStart, partCurPad,
                                                                    nPart, nNodes);
        k_scatterP<<<dim3(nChunks), dim3(256), 0, stream>>>(rows, cols, vals,
                                                            partCurPad, pairsA, nE, nPart);
        k_reorderP<<<dim3(nPart), dim3(1024), 0, stream>>>(rowStart, pairsA, pairsCSR,
                                                           nNodes);

        const int rowsPerBlock = 4;
        dim3 sgrid((nNodes + rowsPerBlock - 1) / rowsPerBlock), sblk(256);
        // spmm1 overwrites pairsA region with cur1 (pairsA dead after reorderP)
        k_spmm1<<<sgrid, sblk, 0, stream>>>(rowStart, pairsCSR, userE, itemE, cur1,
                                            nNodes, nUsers);
        k_spmm2<<<sgrid, sblk, 0, stream>>>(rowStart, pairsCSR, cur1, userE, itemE, out,
                                            nNodes, nUsers);
    } else {
        // fallback: atomic scatter path (round-1)
        hipMemsetAsync(cur1, 0, cur1B, stream);
        dim3 blk(256);
        spmm_scatter<<<dim3(4096), blk, 0, stream>>>(rows, cols, vals, userE, itemE,
                                                     cur1, 1.0f, nE, nUsers);
        finalize_base<<<dim3(2048), blk, 0, stream>>>(userE, itemE, cur1, out,
                                                      nNodes, nUsers);
        spmm_scatter<<<dim3(4096), blk, 0, stream>>>(rows, cols, vals, cur1, nullptr,
                                                     out, 1.0f / 3.0f, nE, nUsers);
    }
}

// Round 8
// 901.309 us; speedup vs baseline: 6.5108x; 1.2659x over previous
//
#include <hip/hip_runtime.h>

#define DIM 64
#define PROWS 2048          // rows per partition (localRow fits 11 bits)
#define MAXPART 256         // supports nNodes <= 524288 (= 2^19 packing limit)
#define CHUNK 8192          // edges per block in pass A

__device__ __forceinline__ float i2f(int x) { union { int i; float f; } u; u.i = x; return u.f; }

// ---------------- partition-level histogram (LDS-aggregated) ----------------
__global__ __launch_bounds__(256) void k_phist(const int* __restrict__ rows,
                                               int* __restrict__ partCnt,
                                               int nE, int nPart) {
    __shared__ int h[MAXPART];
    for (int t = threadIdx.x; t < nPart; t += 256) h[t] = 0;
    __syncthreads();
    for (long i = (long)blockIdx.x * blockDim.x + threadIdx.x; i < nE;
         i += (long)gridDim.x * blockDim.x)
        atomicAdd(&h[rows[i] >> 11], 1);
    __syncthreads();
    for (int t = threadIdx.x; t < nPart; t += 256) {
        int v = h[t];
        if (v) atomicAdd(&partCnt[t], v);
    }
}

// ---------------- single-block scan over partitions ----------------
__global__ __launch_bounds__(256) void k_pscan(const int* __restrict__ partCnt,
                                               int* __restrict__ partStart,
                                               int* __restrict__ partCurPad,
                                               int nPart, int nE) {
    __shared__ int s[256];
    const int t = threadIdx.x;
    int v = (t < nPart) ? partCnt[t] : 0;
    s[t] = v; __syncthreads();
    for (int off = 1; off < 256; off <<= 1) {
        int tmp = (t >= off) ? s[t - off] : 0;
        __syncthreads();
        s[t] += tmp;
        __syncthreads();
    }
    if (t < nPart) {
        int excl = s[t] - v;
        partStart[t] = excl;
        partCurPad[t * 16] = excl;
    }
    if (t == 0) partStart[nPart] = nE;
}

// ---------------- pass A: COO -> partition-ordered pairs ----------------
// Block-chunked counting sort: per-block LDS histogram, one global atomic per
// (block,partition) reserves a contiguous run written entirely by this block.
__global__ __launch_bounds__(256) void k_scatterP(const int* __restrict__ rows,
                                                  const int* __restrict__ cols,
                                                  const float* __restrict__ vals,
                                                  int* __restrict__ partCurPad,
                                                  int2* __restrict__ pairsA,
                                                  int nE, int nPart) {
    __shared__ int hist[MAXPART];
    __shared__ int runBase[MAXPART];
    const int chunkBase = blockIdx.x * CHUNK;

    for (int t = threadIdx.x; t < nPart; t += 256) hist[t] = 0;
    __syncthreads();
    #pragma unroll
    for (int j = 0; j < CHUNK / 256; ++j) {
        int i = chunkBase + j * 256 + threadIdx.x;
        if (i < nE) atomicAdd(&hist[rows[i] >> 11], 1);
    }
    __syncthreads();
    for (int t = threadIdx.x; t < nPart; t += 256) {
        int h = hist[t];
        runBase[t] = h ? atomicAdd(&partCurPad[t * 16], h) : 0;
    }
    __syncthreads();
    for (int t = threadIdx.x; t < nPart; t += 256) hist[t] = 0;   // reuse as rank
    __syncthreads();
    #pragma unroll
    for (int j = 0; j < CHUNK / 256; ++j) {
        int i = chunkBase + j * 256 + threadIdx.x;
        if (i < nE) {
            int r = rows[i];
            int p = r >> 11;
            int rank = atomicAdd(&hist[p], 1);
            pairsA[runBase[p] + rank] =
                make_int2(((r & (PROWS - 1)) << 19) | cols[i], __float_as_int(vals[i]));
        }
    }
}

// ---------------- fused: row-hist + scan + reorder -> exact CSR + rowStart ----
// Block per partition. Sequential reads of the partition span (twice); CSR
// writes confined to the partition's contiguous span (single XCD L2 absorbs).
__global__ __launch_bounds__(1024) void k_buildCSR(const int* __restrict__ partStart,
                                                   const int2* __restrict__ pairsA,
                                                   int2* __restrict__ pairsCSR,
                                                   int* __restrict__ rowStart,
                                                   int nNodes, int nE, int nPart) {
    __shared__ int hist[PROWS];
    __shared__ int cur[PROWS];
    __shared__ int s[1024];
    const int p  = blockIdx.x;
    const int r0 = p * PROWS;
    const int segStart = partStart[p], segEnd = partStart[p + 1];
    const int t = threadIdx.x;

    hist[t] = 0; hist[t + 1024] = 0;
    __syncthreads();
    for (int i = segStart + t; i < segEnd; i += 1024)
        atomicAdd(&hist[pairsA[i].x >> 19], 1);
    __syncthreads();

    // exclusive scan of hist[2048]: 2 elems/thread
    int a0 = hist[2 * t], a1 = hist[2 * t + 1];
    s[t] = a0 + a1;
    __syncthreads();
    for (int off = 1; off < 1024; off <<= 1) {
        int tmp = (t >= off) ? s[t - off] : 0;
        __syncthreads();
        s[t] += tmp;
        __syncthreads();
    }
    int pairExcl = s[t] - (a0 + a1);
    cur[2 * t]     = segStart + pairExcl;
    cur[2 * t + 1] = segStart + pairExcl + a0;
    __syncthreads();

    // write global rowStart (coalesced)
    int rN = nNodes - r0; if (rN > PROWS) rN = PROWS;
    for (int j = t; j < rN; j += 1024) rowStart[r0 + j] = cur[j];
    if (p == nPart - 1 && t == 0) rowStart[nNodes] = nE;
    __syncthreads();

    // scatter to exact CSR positions
    for (int i = segStart + t; i < segEnd; i += 1024) {
        int2 e = pairsA[i];
        int lr = e.x >> 19;
        int pos = atomicAdd(&cur[lr], 1);
        pairsCSR[pos] = make_int2(e.x & 0x7FFFF, e.y);
    }
}

// ---------------- SpMM: one wave per row, lane = dim, unroll x4 ----------------
__global__ __launch_bounds__(256) void k_spmm1(const int* __restrict__ rowStart,
                                               const int2* __restrict__ pairs,
                                               const float* __restrict__ uE,
                                               const float* __restrict__ iE,
                                               float* __restrict__ cur1,
                                               int nNodes, int nUsers) {
    const int lane = threadIdx.x & 63;
    int r = blockIdx.x * (blockDim.x >> 6) + (threadIdx.x >> 6);
    if (r >= nNodes) return;
    int start = __builtin_amdgcn_readfirstlane(rowStart[r]);
    int end   = __builtin_amdgcn_readfirstlane(rowStart[r + 1]);
    float acc = 0.f;
    int e = start;
    for (; e + 3 < end; e += 4) {
        int2 p0 = pairs[e], p1 = pairs[e + 1], p2 = pairs[e + 2], p3 = pairs[e + 3];
        const float* s0 = (p0.x < nUsers) ? uE + (size_t)p0.x * DIM
                                          : iE + (size_t)(p0.x - nUsers) * DIM;
        const float* s1 = (p1.x < nUsers) ? uE + (size_t)p1.x * DIM
                                          : iE + (size_t)(p1.x - nUsers) * DIM;
        const float* s2 = (p2.x < nUsers) ? uE + (size_t)p2.x * DIM
                                          : iE + (size_t)(p2.x - nUsers) * DIM;
        const float* s3 = (p3.x < nUsers) ? uE + (size_t)p3.x * DIM
                                          : iE + (size_t)(p3.x - nUsers) * DIM;
        float x0 = s0[lane], x1 = s1[lane], x2 = s2[lane], x3 = s3[lane];
        acc = fmaf(i2f(p0.y), x0, acc);
        acc = fmaf(i2f(p1.y), x1, acc);
        acc = fmaf(i2f(p2.y), x2, acc);
        acc = fmaf(i2f(p3.y), x3, acc);
    }
    for (; e < end; ++e) {
        int2 p = pairs[e];
        const float* s = (p.x < nUsers) ? uE + (size_t)p.x * DIM
                                        : iE + (size_t)(p.x - nUsers) * DIM;
        acc = fmaf(i2f(p.y), s[lane], acc);
    }
    cur1[(size_t)r * DIM + lane] = acc;
}

__global__ __launch_bounds__(256) void k_spmm2(const int* __restrict__ rowStart,
                                               const int2* __restrict__ pairs,
                                               const float* __restrict__ cur1,
                                               const float* __restrict__ uE,
                                               const float* __restrict__ iE,
                                               float* __restrict__ out,
                                               int nNodes, int nUsers) {
    const int lane = threadIdx.x & 63;
    int r = blockIdx.x * (blockDim.x >> 6) + (threadIdx.x >> 6);
    if (r >= nNodes) return;
    int start = __builtin_amdgcn_readfirstlane(rowStart[r]);
    int end   = __builtin_amdgcn_readfirstlane(rowStart[r + 1]);
    float acc = 0.f;
    int e = start;
    for (; e + 3 < end; e += 4) {
        int2 p0 = pairs[e], p1 = pairs[e + 1], p2 = pairs[e + 2], p3 = pairs[e + 3];
        float x0 = cur1[(size_t)p0.x * DIM + lane];
        float x1 = cur1[(size_t)p1.x * DIM + lane];
        float x2 = cur1[(size_t)p2.x * DIM + lane];
        float x3 = cur1[(size_t)p3.x * DIM + lane];
        acc = fmaf(i2f(p0.y), x0, acc);
        acc = fmaf(i2f(p1.y), x1, acc);
        acc = fmaf(i2f(p2.y), x2, acc);
        acc = fmaf(i2f(p3.y), x3, acc);
    }
    for (; e < end; ++e) {
        int2 p = pairs[e];
        acc = fmaf(i2f(p.y), cur1[(size_t)p.x * DIM + lane], acc);
    }
    float em = (r < nUsers) ? uE[(size_t)r * DIM + lane]
                            : iE[(size_t)(r - nUsers) * DIM + lane];
    out[(size_t)r * DIM + lane] = (em + cur1[(size_t)r * DIM + lane] + acc) * (1.0f / 3.0f);
}

// ---------------- fallback (round-1 atomic path) ----------------
__global__ __launch_bounds__(256) void spmm_scatter(
    const int* __restrict__ rows, const int* __restrict__ cols,
    const float* __restrict__ vals, const float* __restrict__ srcU,
    const float* __restrict__ srcI, float* __restrict__ dst,
    float scale, int nEdges, int nUsers)
{
    const int lane = threadIdx.x & 63;
    const int wavesPerBlock = blockDim.x >> 6;
    long wave = (long)blockIdx.x * wavesPerBlock + (threadIdx.x >> 6);
    const long nWaves = (long)gridDim.x * wavesPerBlock;
    for (long e = wave; e < nEdges; e += nWaves) {
        const int r = rows[e];
        const int c = cols[e];
        const float v = vals[e] * scale;
        const float* src;
        if (srcI != nullptr) {
            src = (c < nUsers) ? (srcU + (size_t)c * DIM)
                               : (srcI + (size_t)(c - nUsers) * DIM);
        } else {
            src = srcU + (size_t)c * DIM;
        }
        atomicAdd(dst + (size_t)r * DIM + lane, v * src[lane]);
    }
}

__global__ __launch_bounds__(256) void finalize_base(
    const float* __restrict__ userE, const float* __restrict__ itemE,
    const float* __restrict__ cur1, float* __restrict__ out, int nNodes, int nUsers)
{
    const long total4 = (long)nNodes * DIM / 4;
    const long user4  = (long)nUsers * DIM / 4;
    const float inv3 = 1.0f / 3.0f;
    for (long i = (long)blockIdx.x * blockDim.x + threadIdx.x; i < total4;
         i += (long)gridDim.x * blockDim.x) {
        float4 e = (i < user4) ? ((const float4*)userE)[i]
                               : ((const float4*)itemE)[i - user4];
        float4 c = ((const float4*)cur1)[i];
        float4 o;
        o.x = (e.x + c.x) * inv3; o.y = (e.y + c.y) * inv3;
        o.z = (e.z + c.z) * inv3; o.w = (e.w + c.w) * inv3;
        ((float4*)out)[i] = o;
    }
}

// ----------------------------------------------------------------

static inline size_t align256(size_t x) { return (x + 255) & ~(size_t)255; }

extern "C" void kernel_launch(void* const* d_in, const int* in_sizes, int n_in,
                              void* d_out, int out_size, void* d_ws, size_t ws_size,
                              hipStream_t stream)
{
    const int*   rows  = (const int*)d_in[0];
    const int*   cols  = (const int*)d_in[1];
    const float* vals  = (const float*)d_in[2];
    const float* userE = (const float*)d_in[3];
    const float* itemE = (const float*)d_in[4];
    float* out = (float*)d_out;

    const int nE     = in_sizes[0];
    const int nUsers = in_sizes[3] / DIM;
    const int nItems = in_sizes[4] / DIM;
    const int nNodes = nUsers + nItems;
    const int nPart  = (nNodes + PROWS - 1) / PROWS;

    // ws layout:
    //   [region0: max(cur1, pairsA)]  pairsA first; spmm1 later overwrites with cur1
    //   [pairsCSR][rowStart][partStart][partCurPad][partCnt]
    const size_t cur1B    = (size_t)nNodes * DIM * sizeof(float);
    const size_t pairsAB  = (size_t)nE * sizeof(int2);
    const size_t reg0B    = cur1B > pairsAB ? cur1B : pairsAB;
    const size_t csrOff   = align256(reg0B);
    const size_t csrB     = (size_t)nE * sizeof(int2);
    const size_t rsOff    = align256(csrOff + csrB);
    const size_t rsB      = ((size_t)nNodes + 1) * sizeof(int);
    const size_t psOff    = align256(rsOff + rsB);
    const size_t psB      = ((size_t)MAXPART + 1) * sizeof(int);
    const size_t pcOff    = align256(psOff + psB);
    const size_t pcB      = (size_t)MAXPART * 16 * sizeof(int);
    const size_t cntOff   = align256(pcOff + pcB);
    const size_t cntB     = (size_t)MAXPART * sizeof(int);
    const size_t required = cntOff + cntB;

    char* ws = (char*)d_ws;
    float* cur1     = (float*)ws;
    int2*  pairsA   = (int2*)ws;                 // same region as cur1
    int2*  pairsCSR = (int2*)(ws + csrOff);

    if (ws_size >= required && nNodes <= MAXPART * PROWS && nNodes < (1 << 19)) {
        int* rowStart   = (int*)(ws + rsOff);
        int* partStart  = (int*)(ws + psOff);
        int* partCurPad = (int*)(ws + pcOff);
        int* partCnt    = (int*)(ws + cntOff);

        const int nChunks = (nE + CHUNK - 1) / CHUNK;

        hipMemsetAsync(partCnt, 0, (size_t)nPart * sizeof(int), stream);
        k_phist<<<dim3(256), dim3(256), 0, stream>>>(rows, partCnt, nE, nPart);
        k_pscan<<<dim3(1), dim3(256), 0, stream>>>(partCnt, partStart, partCurPad,
                                                   nPart, nE);
        k_scatterP<<<dim3(nChunks), dim3(256), 0, stream>>>(rows, cols, vals,
                                                            partCurPad, pairsA, nE, nPart);
        k_buildCSR<<<dim3(nPart), dim3(1024), 0, stream>>>(partStart, pairsA, pairsCSR,
                                                           rowStart, nNodes, nE, nPart);

        const int rowsPerBlock = 4;
        dim3 sgrid((nNodes + rowsPerBlock - 1) / rowsPerBlock), sblk(256);
        // spmm1 overwrites pairsA region with cur1 (pairsA dead after buildCSR)
        k_spmm1<<<sgrid, sblk, 0, stream>>>(rowStart, pairsCSR, userE, itemE, cur1,
                                            nNodes, nUsers);
        k_spmm2<<<sgrid, sblk, 0, stream>>>(rowStart, pairsCSR, cur1, userE, itemE, out,
                                            nNodes, nUsers);
    } else {
        // fallback: atomic scatter path (round-1)
        hipMemsetAsync(cur1, 0, cur1B, stream);
        dim3 blk(256);
        spmm_scatter<<<dim3(4096), blk, 0, stream>>>(rows, cols, vals, userE, itemE,
                                                     cur1, 1.0f, nE, nUsers);
        finalize_base<<<dim3(2048), blk, 0, stream>>>(userE, itemE, cur1, out,
                                                      nNodes, nUsers);
        spmm_scatter<<<dim3(4096), blk, 0, stream>>>(rows, cols, vals, cur1, nullptr,
                                                     out, 1.0f / 3.0f, nE, nUsers);
    }
}

// Round 9
// 851.387 us; speedup vs baseline: 6.8926x; 1.0586x over previous
//
#include <hip/hip_runtime.h>

#define DIM 64
#define PROWS 2048          // rows per partition (localRow fits 11 bits)
#define MAXPART 256         // supports nNodes <= 524288 (= 2^19 packing limit)
#define CHUNK 8192          // edges per block in pass A

__device__ __forceinline__ float i2f(int x) { union { int i; float f; } u; u.i = x; return u.f; }

// ---------------- partition-level histogram (LDS-aggregated) ----------------
__global__ __launch_bounds__(256) void k_phist(const int* __restrict__ rows,
                                               int* __restrict__ partCnt,
                                               int nE, int nPart) {
    __shared__ int h[MAXPART];
    for (int t = threadIdx.x; t < nPart; t += 256) h[t] = 0;
    __syncthreads();
    for (long i = (long)blockIdx.x * blockDim.x + threadIdx.x; i < nE;
         i += (long)gridDim.x * blockDim.x)
        atomicAdd(&h[rows[i] >> 11], 1);
    __syncthreads();
    for (int t = threadIdx.x; t < nPart; t += 256) {
        int v = h[t];
        if (v) atomicAdd(&partCnt[t], v);
    }
}

// ---------------- single-block scan over partitions ----------------
__global__ __launch_bounds__(256) void k_pscan(const int* __restrict__ partCnt,
                                               int* __restrict__ partStart,
                                               int* __restrict__ partCurPad,
                                               int nPart, int nE) {
    __shared__ int s[256];
    const int t = threadIdx.x;
    int v = (t < nPart) ? partCnt[t] : 0;
    s[t] = v; __syncthreads();
    for (int off = 1; off < 256; off <<= 1) {
        int tmp = (t >= off) ? s[t - off] : 0;
        __syncthreads();
        s[t] += tmp;
        __syncthreads();
    }
    if (t < nPart) {
        int excl = s[t] - v;
        partStart[t] = excl;
        partCurPad[t * 16] = excl;
    }
    if (t == 0) partStart[nPart] = nE;
}

// ---------------- pass A: COO -> partition-ordered pairs ----------------
// Block-chunked counting sort; rows cached in registers between the two loops.
__global__ __launch_bounds__(256) void k_scatterP(const int* __restrict__ rows,
                                                  const int* __restrict__ cols,
                                                  const float* __restrict__ vals,
                                                  int* __restrict__ partCurPad,
                                                  int2* __restrict__ pairsA,
                                                  int nE, int nPart) {
    __shared__ int hist[MAXPART];
    __shared__ int runBase[MAXPART];
    const int chunkBase = blockIdx.x * CHUNK;
    int rcache[CHUNK / 256];

    for (int t = threadIdx.x; t < nPart; t += 256) hist[t] = 0;
    __syncthreads();
    #pragma unroll
    for (int j = 0; j < CHUNK / 256; ++j) {
        int i = chunkBase + j * 256 + threadIdx.x;
        int r = (i < nE) ? rows[i] : -1;
        rcache[j] = r;
        if (r >= 0) atomicAdd(&hist[r >> 11], 1);
    }
    __syncthreads();
    for (int t = threadIdx.x; t < nPart; t += 256) {
        int h = hist[t];
        runBase[t] = h ? atomicAdd(&partCurPad[t * 16], h) : 0;
    }
    __syncthreads();
    for (int t = threadIdx.x; t < nPart; t += 256) hist[t] = 0;   // reuse as rank
    __syncthreads();
    #pragma unroll
    for (int j = 0; j < CHUNK / 256; ++j) {
        int i = chunkBase + j * 256 + threadIdx.x;
        int r = rcache[j];
        if (r >= 0) {
            int p = r >> 11;
            int rank = atomicAdd(&hist[p], 1);
            pairsA[runBase[p] + rank] =
                make_int2(((r & (PROWS - 1)) << 19) | cols[i], __float_as_int(vals[i]));
        }
    }
}

// ---------------- fused: row-hist + scan + reorder -> exact CSR + rowStart ----
__global__ __launch_bounds__(1024) void k_buildCSR(const int* __restrict__ partStart,
                                                   const int2* __restrict__ pairsA,
                                                   int2* __restrict__ pairsCSR,
                                                   int* __restrict__ rowStart,
                                                   int nNodes, int nE, int nPart) {
    __shared__ int hist[PROWS];
    __shared__ int cur[PROWS];
    __shared__ int s[1024];
    const int p  = blockIdx.x;
    const int r0 = p * PROWS;
    const int segStart = partStart[p], segEnd = partStart[p + 1];
    const int t = threadIdx.x;

    hist[t] = 0; hist[t + 1024] = 0;
    __syncthreads();
    for (int i = segStart + t; i < segEnd; i += 1024)
        atomicAdd(&hist[pairsA[i].x >> 19], 1);
    __syncthreads();

    int a0 = hist[2 * t], a1 = hist[2 * t + 1];
    s[t] = a0 + a1;
    __syncthreads();
    for (int off = 1; off < 1024; off <<= 1) {
        int tmp = (t >= off) ? s[t - off] : 0;
        __syncthreads();
        s[t] += tmp;
        __syncthreads();
    }
    int pairExcl = s[t] - (a0 + a1);
    cur[2 * t]     = segStart + pairExcl;
    cur[2 * t + 1] = segStart + pairExcl + a0;
    __syncthreads();

    int rN = nNodes - r0; if (rN > PROWS) rN = PROWS;
    for (int j = t; j < rN; j += 1024) rowStart[r0 + j] = cur[j];
    if (p == nPart - 1 && t == 0) rowStart[nNodes] = nE;
    __syncthreads();

    for (int i = segStart + t; i < segEnd; i += 1024) {
        int2 e = pairsA[i];
        int lr = e.x >> 19;
        int pos = atomicAdd(&cur[lr], 1);
        pairsCSR[pos] = make_int2(e.x & 0x7FFFF, e.y);
    }
}

// ---------------- SpMM: one wave per row, lane = dim, unroll x8 ----------------
__global__ __launch_bounds__(256) void k_spmm1(const int* __restrict__ rowStart,
                                               const int2* __restrict__ pairs,
                                               const float* __restrict__ uE,
                                               const float* __restrict__ iE,
                                               float* __restrict__ cur1,
                                               int nNodes, int nUsers) {
    const int lane = threadIdx.x & 63;
    int r = blockIdx.x * (blockDim.x >> 6) + (threadIdx.x >> 6);
    if (r >= nNodes) return;
    int start = __builtin_amdgcn_readfirstlane(rowStart[r]);
    int end   = __builtin_amdgcn_readfirstlane(rowStart[r + 1]);
    float acc = 0.f;
    int e = start;
    for (; e + 7 < end; e += 8) {
        int2 p[8]; float x[8];
        #pragma unroll
        for (int j = 0; j < 8; ++j) p[j] = pairs[e + j];
        #pragma unroll
        for (int j = 0; j < 8; ++j) {
            const float* s = (p[j].x < nUsers) ? uE + (size_t)p[j].x * DIM
                                               : iE + (size_t)(p[j].x - nUsers) * DIM;
            x[j] = s[lane];
        }
        #pragma unroll
        for (int j = 0; j < 8; ++j) acc = fmaf(i2f(p[j].y), x[j], acc);
    }
    for (; e + 3 < end; e += 4) {
        int2 p[4]; float x[4];
        #pragma unroll
        for (int j = 0; j < 4; ++j) p[j] = pairs[e + j];
        #pragma unroll
        for (int j = 0; j < 4; ++j) {
            const float* s = (p[j].x < nUsers) ? uE + (size_t)p[j].x * DIM
                                               : iE + (size_t)(p[j].x - nUsers) * DIM;
            x[j] = s[lane];
        }
        #pragma unroll
        for (int j = 0; j < 4; ++j) acc = fmaf(i2f(p[j].y), x[j], acc);
    }
    for (; e < end; ++e) {
        int2 p = pairs[e];
        const float* s = (p.x < nUsers) ? uE + (size_t)p.x * DIM
                                        : iE + (size_t)(p.x - nUsers) * DIM;
        acc = fmaf(i2f(p.y), s[lane], acc);
    }
    cur1[(size_t)r * DIM + lane] = acc;
}

__global__ __launch_bounds__(256) void k_spmm2(const int* __restrict__ rowStart,
                                               const int2* __restrict__ pairs,
                                               const float* __restrict__ cur1,
                                               const float* __restrict__ uE,
                                               const float* __restrict__ iE,
                                               float* __restrict__ out,
                                               int nNodes, int nUsers) {
    const int lane = threadIdx.x & 63;
    int r = blockIdx.x * (blockDim.x >> 6) + (threadIdx.x >> 6);
    if (r >= nNodes) return;
    int start = __builtin_amdgcn_readfirstlane(rowStart[r]);
    int end   = __builtin_amdgcn_readfirstlane(rowStart[r + 1]);
    float acc = 0.f;
    int e = start;
    for (; e + 7 < end; e += 8) {
        int2 p[8]; float x[8];
        #pragma unroll
        for (int j = 0; j < 8; ++j) p[j] = pairs[e + j];
        #pragma unroll
        for (int j = 0; j < 8; ++j) x[j] = cur1[(size_t)p[j].x * DIM + lane];
        #pragma unroll
        for (int j = 0; j < 8; ++j) acc = fmaf(i2f(p[j].y), x[j], acc);
    }
    for (; e + 3 < end; e += 4) {
        int2 p[4]; float x[4];
        #pragma unroll
        for (int j = 0; j < 4; ++j) p[j] = pairs[e + j];
        #pragma unroll
        for (int j = 0; j < 4; ++j) x[j] = cur1[(size_t)p[j].x * DIM + lane];
        #pragma unroll
        for (int j = 0; j < 4; ++j) acc = fmaf(i2f(p[j].y), x[j], acc);
    }
    for (; e < end; ++e) {
        int2 p = pairs[e];
        acc = fmaf(i2f(p.y), cur1[(size_t)p.x * DIM + lane], acc);
    }
    float em = (r < nUsers) ? uE[(size_t)r * DIM + lane]
                            : iE[(size_t)(r - nUsers) * DIM + lane];
    float o = (em + cur1[(size_t)r * DIM + lane] + acc) * (1.0f / 3.0f);
    __builtin_nontemporal_store(o, &out[(size_t)r * DIM + lane]);
}

// ---------------- fallback (round-1 atomic path) ----------------
__global__ __launch_bounds__(256) void spmm_scatter(
    const int* __restrict__ rows, const int* __restrict__ cols,
    const float* __restrict__ vals, const float* __restrict__ srcU,
    const float* __restrict__ srcI, float* __restrict__ dst,
    float scale, int nEdges, int nUsers)
{
    const int lane = threadIdx.x & 63;
    const int wavesPerBlock = blockDim.x >> 6;
    long wave = (long)blockIdx.x * wavesPerBlock + (threadIdx.x >> 6);
    const long nWaves = (long)gridDim.x * wavesPerBlock;
    for (long e = wave; e < nEdges; e += nWaves) {
        const int r = rows[e];
        const int c = cols[e];
        const float v = vals[e] * scale;
        const float* src;
        if (srcI != nullptr) {
            src = (c < nUsers) ? (srcU + (size_t)c * DIM)
                               : (srcI + (size_t)(c - nUsers) * DIM);
        } else {
            src = srcU + (size_t)c * DIM;
        }
        atomicAdd(dst + (size_t)r * DIM + lane, v * src[lane]);
    }
}

__global__ __launch_bounds__(256) void finalize_base(
    const float* __restrict__ userE, const float* __restrict__ itemE,
    const float* __restrict__ cur1, float* __restrict__ out, int nNodes, int nUsers)
{
    const long total4 = (long)nNodes * DIM / 4;
    const long user4  = (long)nUsers * DIM / 4;
    const float inv3 = 1.0f / 3.0f;
    for (long i = (long)blockIdx.x * blockDim.x + threadIdx.x; i < total4;
         i += (long)gridDim.x * blockDim.x) {
        float4 e = (i < user4) ? ((const float4*)userE)[i]
                               : ((const float4*)itemE)[i - user4];
        float4 c = ((const float4*)cur1)[i];
        float4 o;
        o.x = (e.x + c.x) * inv3; o.y = (e.y + c.y) * inv3;
        o.z = (e.z + c.z) * inv3; o.w = (e.w + c.w) * inv3;
        ((float4*)out)[i] = o;
    }
}

// ----------------------------------------------------------------

static inline size_t align256(size_t x) { return (x + 255) & ~(size_t)255; }

extern "C" void kernel_launch(void* const* d_in, const int* in_sizes, int n_in,
                              void* d_out, int out_size, void* d_ws, size_t ws_size,
                              hipStream_t stream)
{
    const int*   rows  = (const int*)d_in[0];
    const int*   cols  = (const int*)d_in[1];
    const float* vals  = (const float*)d_in[2];
    const float* userE = (const float*)d_in[3];
    const float* itemE = (const float*)d_in[4];
    float* out = (float*)d_out;

    const int nE     = in_sizes[0];
    const int nUsers = in_sizes[3] / DIM;
    const int nItems = in_sizes[4] / DIM;
    const int nNodes = nUsers + nItems;
    const int nPart  = (nNodes + PROWS - 1) / PROWS;

    // ws layout:
    //   [region0: max(cur1, pairsA)]  pairsA first; spmm1 later overwrites with cur1
    //   [pairsCSR][rowStart][partStart][partCurPad][partCnt]
    const size_t cur1B    = (size_t)nNodes * DIM * sizeof(float);
    const size_t pairsAB  = (size_t)nE * sizeof(int2);
    const size_t reg0B    = cur1B > pairsAB ? cur1B : pairsAB;
    const size_t csrOff   = align256(reg0B);
    const size_t csrB     = (size_t)nE * sizeof(int2);
    const size_t rsOff    = align256(csrOff + csrB);
    const size_t rsB      = ((size_t)nNodes + 1) * sizeof(int);
    const size_t psOff    = align256(rsOff + rsB);
    const size_t psB      = ((size_t)MAXPART + 1) * sizeof(int);
    const size_t pcOff    = align256(psOff + psB);
    const size_t pcB      = (size_t)MAXPART * 16 * sizeof(int);
    const size_t cntOff   = align256(pcOff + pcB);
    const size_t cntB     = (size_t)MAXPART * sizeof(int);
    const size_t required = cntOff + cntB;

    char* ws = (char*)d_ws;
    float* cur1     = (float*)ws;
    int2*  pairsA   = (int2*)ws;                 // same region as cur1
    int2*  pairsCSR = (int2*)(ws + csrOff);

    if (ws_size >= required && nNodes <= MAXPART * PROWS && nNodes < (1 << 19)) {
        int* rowStart   = (int*)(ws + rsOff);
        int* partStart  = (int*)(ws + psOff);
        int* partCurPad = (int*)(ws + pcOff);
        int* partCnt    = (int*)(ws + cntOff);

        const int nChunks = (nE + CHUNK - 1) / CHUNK;

        hipMemsetAsync(partCnt, 0, (size_t)nPart * sizeof(int), stream);
        k_phist<<<dim3(512), dim3(256), 0, stream>>>(rows, partCnt, nE, nPart);
        k_pscan<<<dim3(1), dim3(256), 0, stream>>>(partCnt, partStart, partCurPad,
                                                   nPart, nE);
        k_scatterP<<<dim3(nChunks), dim3(256), 0, stream>>>(rows, cols, vals,
                                                            partCurPad, pairsA, nE, nPart);
        k_buildCSR<<<dim3(nPart), dim3(1024), 0, stream>>>(partStart, pairsA, pairsCSR,
                                                           rowStart, nNodes, nE, nPart);

        const int rowsPerBlock = 4;
        dim3 sgrid((nNodes + rowsPerBlock - 1) / rowsPerBlock), sblk(256);
        // spmm1 overwrites pairsA region with cur1 (pairsA dead after buildCSR)
        k_spmm1<<<sgrid, sblk, 0, stream>>>(rowStart, pairsCSR, userE, itemE, cur1,
                                            nNodes, nUsers);
        k_spmm2<<<sgrid, sblk, 0, stream>>>(rowStart, pairsCSR, cur1, userE, itemE, out,
                                            nNodes, nUsers);
    } else {
        // fallback: atomic scatter path (round-1)
        hipMemsetAsync(cur1, 0, cur1B, stream);
        dim3 blk(256);
        spmm_scatter<<<dim3(4096), blk, 0, stream>>>(rows, cols, vals, userE, itemE,
                                                     cur1, 1.0f, nE, nUsers);
        finalize_base<<<dim3(2048), blk, 0, stream>>>(userE, itemE, cur1, out,
                                                      nNodes, nUsers);
        spmm_scatter<<<dim3(4096), blk, 0, stream>>>(rows, cols, vals, cur1, nullptr,
                                                     out, 1.0f / 3.0f, nE, nUsers);
    }
}